// Round 11
// baseline (1052.401 us; speedup 1.0000x reference)
//
#include <hip/hip_runtime.h>
#include <hip/hip_bf16.h>

typedef __attribute__((ext_vector_type(4))) float f32x4;
typedef __attribute__((ext_vector_type(8))) short s16x8;
typedef unsigned short ushort_t;

// ---------- helpers ----------
__device__ __forceinline__ ushort_t f2bf(float f) {
    union { float f; unsigned u; } v; v.f = f;
    unsigned r = v.u + 0x7fffu + ((v.u >> 16) & 1u);   // RNE
    return (ushort_t)(r >> 16);
}

__device__ __forceinline__ void gload16(const ushort_t* g, ushort_t* l) {
    __builtin_amdgcn_global_load_lds(
        (const __attribute__((address_space(1))) unsigned int*)g,
        (__attribute__((address_space(3))) unsigned int*)l,
        16, 0, 0);
}

#define BAR()  asm volatile("s_barrier" ::: "memory")
#define LGK0() do { asm volatile("s_waitcnt lgkmcnt(0)" ::: "memory"); __builtin_amdgcn_sched_barrier(0); } while (0)
#define VMC(n) asm volatile("s_waitcnt vmcnt(" #n ")" ::: "memory")

// ---------- fp32 -> bf16 conversion (8 elems/thread) ----------
__global__ void cvt_bf16(const float* __restrict__ in, ushort_t* __restrict__ out, int n8) {
    int i = blockIdx.x * blockDim.x + threadIdx.x;
    if (i >= n8) return;
    const float4* p = (const float4*)in;
    float4 a = p[2 * i], b = p[2 * i + 1];
    s16x8 v;
    v[0] = (short)f2bf(a.x); v[1] = (short)f2bf(a.y);
    v[2] = (short)f2bf(a.z); v[3] = (short)f2bf(a.w);
    v[4] = (short)f2bf(b.x); v[5] = (short)f2bf(b.y);
    v[6] = (short)f2bf(b.z); v[7] = (short)f2bf(b.w);
    *(s16x8*)(out + (size_t)i * 8) = v;
}

// 4 weight matrices (E*E each) -> contiguous bf16 [Wq;Wk;Wv;Wo]
__global__ void cvt_w4(const float* __restrict__ w0, const float* __restrict__ w1,
                       const float* __restrict__ w2, const float* __restrict__ w3,
                       ushort_t* __restrict__ out) {
    const float* src = (blockIdx.y == 0) ? w0 : (blockIdx.y == 1) ? w1
                     : (blockIdx.y == 2) ? w2 : w3;
    ushort_t* dst = out + (size_t)blockIdx.y * 1024 * 1024;
    int i = blockIdx.x * blockDim.x + threadIdx.x;   // 131072 per matrix
    const float4* p = (const float4*)src;
    float4 a = p[2 * i], b = p[2 * i + 1];
    s16x8 v;
    v[0] = (short)f2bf(a.x); v[1] = (short)f2bf(a.y);
    v[2] = (short)f2bf(a.z); v[3] = (short)f2bf(a.w);
    v[4] = (short)f2bf(b.x); v[5] = (short)f2bf(b.y);
    v[6] = (short)f2bf(b.z); v[7] = (short)f2bf(b.w);
    *(s16x8*)(dst + (size_t)i * 8) = v;
}

// ---------- RoPE tables ----------
__global__ void rope_tab_k(float* __restrict__ cosT, float* __restrict__ sinT) {
    int i = blockIdx.x * blockDim.x + threadIdx.x;   // 8192 total
    int l = i >> 5, fi = i & 31;
    float inv = powf(10000.f, -2.f * (float)fi / 64.f);
    float ang = (float)l * inv;
    cosT[i] = cosf(ang);
    sinT[i] = sinf(ang);
}

// ---------- 128x256 GEMM, BK=32, dbuf, 3 blocks/CU ----------
// Round-9 structure (best measured) + occupancy 3 blocks/CU:
// 8 waves (2Mx4N), wave tile 64x64, acc[4][4], 56 VGPR; LDS 2 x 24 KiB = 48 KiB
// -> 3 blocks/CU (144 KiB of 160; 6 waves/SIMD needs <=85 VGPR, have 56).
// Depth-1 prefetch, ONE VMC(0)+BAR per K-tile (collective guard, round-4/5
// protocol); co-resident blocks fill the drain stall (m114 TLP). Depth-2
// rejected: round-10 showed +70MB HBM refetch from L2 thrash, net regression.
// Swizzle f(row)=(row>>1)&3: conflict-free (0 conflicts, rounds 6-10).

__device__ __forceinline__ void stageA32(const ushort_t* __restrict__ src,
                                         ushort_t* chunk, int tid, int kk) {
    int row = tid >> 2;                       // 128 rows x 4 slots
    int gslot = (tid & 3) ^ ((row >> 1) & 3);
    gload16(src + (size_t)row * 1024 + kk + gslot * 8, chunk + (size_t)tid * 8);
}
__device__ __forceinline__ void stageB32(const ushort_t* __restrict__ src,
                                         ushort_t* chunk, int tid, int kk) {
#pragma unroll
    for (int j = 0; j < 2; ++j) {
        int row = (tid >> 2) + j * 128;       // 256 rows x 4 slots
        int gslot = (tid & 3) ^ ((row >> 1) & 3);
        gload16(src + (size_t)row * 1024 + kk + gslot * 8,
                chunk + (size_t)tid * 8 + (size_t)j * 4096);
    }
}

__device__ __forceinline__ s16x8 rdA32(const ushort_t* chunk, int wm, int m, int lane) {
    int row = wm * 64 + m * 16 + (lane & 15);
    int slot = (lane >> 4) ^ ((row >> 1) & 3);
    return *(const s16x8*)&chunk[row * 32 + (slot << 3)];
}
__device__ __forceinline__ s16x8 rdB32(const ushort_t* chunk, int wn, int n, int lane) {
    int row = wn * 64 + n * 16 + (lane & 15);
    int slot = (lane >> 4) ^ ((row >> 1) & 3);
    return *(const s16x8*)&chunk[row * 32 + (slot << 3)];
}

// MODE 0: fused QKV (N=3072 -> q/k/v bf16 + bias + rope on q,k), ntn=12
// MODE 1: out-proj (N=1024 -> fp32 + bias), ntn=4
template <int MODE>
__global__ __launch_bounds__(512, 6) void gemm128(const ushort_t* __restrict__ A,
                                                  const ushort_t* __restrict__ Wt,
                                                  const float* __restrict__ bz0,
                                                  const float* __restrict__ bz1,
                                                  const float* __restrict__ bz2,
                                                  ushort_t* __restrict__ o0,
                                                  ushort_t* __restrict__ o1,
                                                  ushort_t* __restrict__ o2,
                                                  float* __restrict__ of,
                                                  const float* __restrict__ cosT,
                                                  const float* __restrict__ sinT,
                                                  int ntn) {
    __shared__ ushort_t lds[2][12288];   // per buf: A [0..4096), B [4096..12288)

    const int nwg = 128 * ntn;
    const int orig = blockIdx.x;
    const int wg = (orig % 8) * (nwg / 8) + orig / 8;   // bijective XCD swizzle (nwg%8==0)
    const int tn = wg % ntn, tm = wg / ntn;             // tn fastest: A-panel L2 reuse

    const int tid = threadIdx.x, lane = tid & 63, wid = tid >> 6;
    const int wm = wid >> 2, wn = wid & 3;

    f32x4 acc[4][4];
#pragma unroll
    for (int i = 0; i < 4; ++i)
#pragma unroll
        for (int j = 0; j < 4; ++j) acc[i][j] = (f32x4){0.f, 0.f, 0.f, 0.f};

    const ushort_t* Abase = A + (size_t)(tm * 128) * 1024;
    const ushort_t* Bbase = Wt + (size_t)(tn * 256) * 1024;

    // ---- prologue: stage tile 0 into buf 0; collective guard ----
    stageA32(Abase, &lds[0][0], tid, 0);
    stageB32(Bbase, &lds[0][4096], tid, 0);
    VMC(0);
    BAR();

    // ---- main loop: 32 K-tiles, one barrier each, depth-1 prefetch ----
#pragma unroll 1
    for (int u = 0; u < 32; ++u) {
        const int cur = u & 1;
        const ushort_t* cA = &lds[cur][0];
        const ushort_t* cB = &lds[cur][4096];
        ushort_t* nA = &lds[cur ^ 1][0];
        ushort_t* nB = &lds[cur ^ 1][4096];
        const int kt = (u + 1 < 32 ? u + 1 : 31) * 32;   // clamp: tail writes unread buf
        s16x8 b_[4], a_[2], a2_[2];

#pragma unroll
        for (int n = 0; n < 4; ++n) b_[n] = rdB32(cB, wn, n, lane);
        a_[0] = rdA32(cA, wm, 0, lane); a_[1] = rdA32(cA, wm, 1, lane);
        stageA32(Abase, nA, tid, kt);
        LGK0();
        __builtin_amdgcn_s_setprio(1);
#pragma unroll
        for (int m = 0; m < 2; ++m)
#pragma unroll
            for (int n = 0; n < 4; ++n)
                acc[m][n] = __builtin_amdgcn_mfma_f32_16x16x32_bf16(a_[m], b_[n], acc[m][n], 0, 0, 0);
        __builtin_amdgcn_s_setprio(0);

        a2_[0] = rdA32(cA, wm, 2, lane); a2_[1] = rdA32(cA, wm, 3, lane);
        stageB32(Bbase, nB, tid, kt);
        LGK0();
        __builtin_amdgcn_s_setprio(1);
#pragma unroll
        for (int m = 0; m < 2; ++m)
#pragma unroll
            for (int n = 0; n < 4; ++n)
                acc[m + 2][n] = __builtin_amdgcn_mfma_f32_16x16x32_bf16(a2_[m], b_[n], acc[m + 2][n], 0, 0, 0);
        __builtin_amdgcn_s_setprio(0);

        VMC(0);    // tile u+1 fully landed (per-wave) ...
        BAR();     // ... made collective; also closes WAR window for next stage
    }

    // ---- epilogue ----
    const int rb0 = tm * 128 + wm * 64 + ((lane >> 4) << 2);
    if (MODE == 0) {
        const int zz = tn >> 2;                                  // uniform per block
        const float* bias = (zz == 0) ? bz0 : (zz == 1) ? bz1 : bz2;
        ushort_t* outp = (zz == 0) ? o0 : (zz == 1) ? o1 : o2;
        const bool rope = (zz < 2);
        const int cb = (tn & 3) * 256 + wn * 64;
#pragma unroll
        for (int m = 0; m < 4; ++m) {
#pragma unroll
            for (int n = 0; n < 4; ++n) {
                int col = cb + n * 16 + (lane & 15);
                float bv_ = bias[col];
                int rb = rb0 + m * 16;
#pragma unroll
                for (int r = 0; r < 4; ++r) {
                    float v = acc[m][n][r] + bv_;
                    float res;
                    if (rope) {
                        int l = (rb + r) & 255;
                        int fi = (col & 63) >> 1;
                        float c = cosT[l * 32 + fi], s = sinT[l * 32 + fi];
                        float partner = __shfl_xor(v, 1);
                        res = (col & 1) ? (v * c + partner * s) : (v * c - partner * s);
                    } else {
                        res = v;
                    }
                    outp[(size_t)(rb + r) * 1024 + col] = f2bf(res);
                }
            }
        }
    } else {
        const int cfull = tn * 256 + wn * 64;
#pragma unroll
        for (int m = 0; m < 4; ++m) {
#pragma unroll
            for (int n = 0; n < 4; ++n) {
                int col = cfull + n * 16 + (lane & 15);
                float bv_ = bz0[col];
                int rb = rb0 + m * 16;
#pragma unroll
                for (int r = 0; r < 4; ++r)
                    of[(size_t)(rb + r) * 1024 + col] = acc[m][n][r] + bv_;
            }
        }
    }
}

// ---------- fused causal attention per (b,h) (unchanged from round 8) ----------
__global__ __launch_bounds__(512, 4) void attn_kernel(const ushort_t* __restrict__ qb,
                                                      const ushort_t* __restrict__ kb,
                                                      const ushort_t* __restrict__ vb,
                                                      ushort_t* __restrict__ ab) {
    __shared__ ushort_t Ks[256 * 72];      // 36864 B
    __shared__ ushort_t Vt[64 * 264];      // 33792 B
    __shared__ ushort_t Ps[8][16 * 40];    // 10240 B
    const int bh = blockIdx.x, b = bh >> 4, h = bh & 15;
    const int tid = threadIdx.x, lane = tid & 63, wid = tid >> 6;
    const size_t base = (size_t)b * 256 * 1024 + (size_t)h * 64;

#pragma unroll
    for (int it = 0; it < 4; ++it) {
        int c = tid + it * 512;
        int row = c >> 3, seg = c & 7;
        *(s16x8*)&Ks[row * 72 + seg * 8] =
            *(const s16x8*)&kb[base + (size_t)row * 1024 + seg * 8];
    }
#pragma unroll
    for (int it = 0; it < 4; ++it) {
        int c = tid + it * 512;
        int k = c >> 3, seg = c & 7;
        s16x8 v8 = *(const s16x8*)&vb[base + (size_t)k * 1024 + seg * 8];
#pragma unroll
        for (int j = 0; j < 8; ++j)
            Vt[(seg * 8 + j) * 264 + k] = (ushort_t)v8[j];
    }
    __syncthreads();   // only barrier in the kernel

#pragma unroll
    for (int ch = 0; ch < 2; ++ch) {
        const int q0 = wid * 32 + ch * 16;
        const int ntop = q0 >> 4;
        s16x8 aq0 = *(const s16x8*)&qb[base + (size_t)(q0 + (lane & 15)) * 1024 + ((lane >> 4) << 3)];
        s16x8 aq1 = *(const s16x8*)&qb[base + (size_t)(q0 + (lane & 15)) * 1024 + 32 + ((lane >> 4) << 3)];

        f32x4 sacc[16];
#pragma unroll
        for (int n = 0; n < 16; ++n) sacc[n] = (f32x4){0.f, 0.f, 0.f, 0.f};
#pragma unroll
        for (int n = 0; n < 16; ++n) {
            if (n <= ntop) {
                const int kr = (n * 16 + (lane & 15)) * 72 + ((lane >> 4) << 3);
                s16x8 b0 = *(const s16x8*)&Ks[kr];
                s16x8 b1 = *(const s16x8*)&Ks[kr + 32];
                sacc[n] = __builtin_amdgcn_mfma_f32_16x16x32_bf16(aq0, b0, sacc[n], 0, 0, 0);
                sacc[n] = __builtin_amdgcn_mfma_f32_16x16x32_bf16(aq1, b1, sacc[n], 0, 0, 0);
            }
        }

        float rinv[4];
#pragma unroll
        for (int r = 0; r < 4; ++r) {
            const int row = q0 + ((lane >> 4) << 2) + r;
            float m = -1e30f;
#pragma unroll
            for (int n = 0; n < 16; ++n) {
                int col = n * 16 + (lane & 15);
                float v = (col <= row) ? sacc[n][r] * 0.125f : -1e30f;
                sacc[n][r] = v;
                m = fmaxf(m, v);
            }
            m = fmaxf(m, __shfl_xor(m, 1));
            m = fmaxf(m, __shfl_xor(m, 2));
            m = fmaxf(m, __shfl_xor(m, 4));
            m = fmaxf(m, __shfl_xor(m, 8));
            float sum = 0.f;
#pragma unroll
            for (int n = 0; n < 16; ++n) {
                float p = __expf(sacc[n][r] - m);
                sacc[n][r] = p;
                sum += p;
            }
            sum += __shfl_xor(sum, 1);
            sum += __shfl_xor(sum, 2);
            sum += __shfl_xor(sum, 4);
            sum += __shfl_xor(sum, 8);
            rinv[r] = 1.f / sum;
        }

        f32x4 oa[4];
#pragma unroll
        for (int dt = 0; dt < 4; ++dt) oa[dt] = (f32x4){0.f, 0.f, 0.f, 0.f};
        const int kstop = q0 >> 5;
#pragma unroll
        for (int ks = 0; ks < 8; ++ks) {
            if (ks <= kstop) {
#pragma unroll
                for (int nl = 0; nl < 2; ++nl) {
                    const int n = 2 * ks + nl;
#pragma unroll
                    for (int r = 0; r < 4; ++r)
                        Ps[wid][(((lane >> 4) << 2) + r) * 40 + nl * 16 + (lane & 15)] =
                            f2bf(sacc[n][r]);
                }
                s16x8 pf = *(const s16x8*)&Ps[wid][(lane & 15) * 40 + ((lane >> 4) << 3)];
#pragma unroll
                for (int dt = 0; dt < 4; ++dt) {
                    s16x8 vf = *(const s16x8*)&Vt[(dt * 16 + (lane & 15)) * 264 + ks * 32 + ((lane >> 4) << 3)];
                    oa[dt] = __builtin_amdgcn_mfma_f32_16x16x32_bf16(pf, vf, oa[dt], 0, 0, 0);
                }
            }
        }
#pragma unroll
        for (int dt = 0; dt < 4; ++dt) {
#pragma unroll
            for (int r = 0; r < 4; ++r) {
                int row = q0 + ((lane >> 4) << 2) + r;
                int col = h * 64 + dt * 16 + (lane & 15);
                ab[(size_t)(b * 256 + row) * 1024 + col] = f2bf(oa[dt][r] * rinv[r]);
            }
        }
    }
}

// ---------- launch ----------
extern "C" void kernel_launch(void* const* d_in, const int* in_sizes, int n_in,
                              void* d_out, int out_size, void* d_ws, size_t ws_size,
                              hipStream_t stream) {
    (void)in_sizes; (void)n_in; (void)out_size;
    const float* x  = (const float*)d_in[0];
    const float* Wq = (const float*)d_in[1];
    const float* bq = (const float*)d_in[2];
    const float* Wk = (const float*)d_in[3];
    const float* bk = (const float*)d_in[4];
    const float* Wv = (const float*)d_in[5];
    const float* bv = (const float*)d_in[6];
    const float* Wo = (const float*)d_in[7];
    const float* bo = (const float*)d_in[8];
    float* out = (float*)d_out;

    const size_t M = 16384, E = 1024;
    char* ws = (char*)d_ws;
    ushort_t* xb   = (ushort_t*)ws;          // M*E (aliased as attn out later)
    ushort_t* wqkv = xb + M * E;             // 4*E*E, concat [Wq;Wk;Wv;Wo]
    ushort_t* wob  = wqkv + 3 * E * E;
    ushort_t* qb   = wob + E * E;
    ushort_t* kb   = qb + M * E;
    ushort_t* vb   = kb + M * E;
    float* cosT    = (float*)(vb + M * E);
    float* sinT    = cosT + 256 * 32;
    ushort_t* ab   = xb;

    size_t need = (4 * M * E + 4 * E * E) * sizeof(ushort_t) + 2 * 256 * 32 * sizeof(float);
    if (ws_size < need) return;

    cvt_bf16<<<8192, 256, 0, stream>>>(x, xb, (int)(M * E / 8));
    cvt_w4<<<dim3(512, 4), 256, 0, stream>>>(Wq, Wk, Wv, Wo, wqkv);
    rope_tab_k<<<32, 256, 0, stream>>>(cosT, sinT);

    gemm128<0><<<1536, 512, 0, stream>>>(xb, wqkv, bq, bk, bv, qb, kb, vb, nullptr,
                                         cosT, sinT, 12);
    attn_kernel<<<1024, 512, 0, stream>>>(qb, kb, vb, ab);
    gemm128<1><<<512, 512, 0, stream>>>(ab, wob, bo, nullptr, nullptr,
                                        nullptr, nullptr, nullptr, out, nullptr, nullptr, 4);
}

// Round 12
// 264.958 us; speedup vs baseline: 3.9720x; 3.9720x over previous
//
#include <hip/hip_runtime.h>
#include <hip/hip_bf16.h>

typedef __attribute__((ext_vector_type(4))) float f32x4;
typedef __attribute__((ext_vector_type(8))) short s16x8;
typedef unsigned short ushort_t;

// ---------- helpers ----------
__device__ __forceinline__ ushort_t f2bf(float f) {
    union { float f; unsigned u; } v; v.f = f;
    unsigned r = v.u + 0x7fffu + ((v.u >> 16) & 1u);   // RNE
    return (ushort_t)(r >> 16);
}

__device__ __forceinline__ void gload16(const ushort_t* g, ushort_t* l) {
    __builtin_amdgcn_global_load_lds(
        (const __attribute__((address_space(1))) unsigned int*)g,
        (__attribute__((address_space(3))) unsigned int*)l,
        16, 0, 0);
}

#define BAR()  asm volatile("s_barrier" ::: "memory")
#define LGK0() do { asm volatile("s_waitcnt lgkmcnt(0)" ::: "memory"); __builtin_amdgcn_sched_barrier(0); } while (0)
#define VMC(n) asm volatile("s_waitcnt vmcnt(" #n ")" ::: "memory")

// ---------- fp32 -> bf16 conversion (8 elems/thread) ----------
__global__ void cvt_bf16(const float* __restrict__ in, ushort_t* __restrict__ out, int n8) {
    int i = blockIdx.x * blockDim.x + threadIdx.x;
    if (i >= n8) return;
    const float4* p = (const float4*)in;
    float4 a = p[2 * i], b = p[2 * i + 1];
    s16x8 v;
    v[0] = (short)f2bf(a.x); v[1] = (short)f2bf(a.y);
    v[2] = (short)f2bf(a.z); v[3] = (short)f2bf(a.w);
    v[4] = (short)f2bf(b.x); v[5] = (short)f2bf(b.y);
    v[6] = (short)f2bf(b.z); v[7] = (short)f2bf(b.w);
    *(s16x8*)(out + (size_t)i * 8) = v;
}

// 4 weight matrices (E*E each) -> contiguous bf16 [Wq;Wk;Wv;Wo]
__global__ void cvt_w4(const float* __restrict__ w0, const float* __restrict__ w1,
                       const float* __restrict__ w2, const float* __restrict__ w3,
                       ushort_t* __restrict__ out) {
    const float* src = (blockIdx.y == 0) ? w0 : (blockIdx.y == 1) ? w1
                     : (blockIdx.y == 2) ? w2 : w3;
    ushort_t* dst = out + (size_t)blockIdx.y * 1024 * 1024;
    int i = blockIdx.x * blockDim.x + threadIdx.x;   // 131072 per matrix
    const float4* p = (const float4*)src;
    float4 a = p[2 * i], b = p[2 * i + 1];
    s16x8 v;
    v[0] = (short)f2bf(a.x); v[1] = (short)f2bf(a.y);
    v[2] = (short)f2bf(a.z); v[3] = (short)f2bf(a.w);
    v[4] = (short)f2bf(b.x); v[5] = (short)f2bf(b.y);
    v[6] = (short)f2bf(b.z); v[7] = (short)f2bf(b.w);
    *(s16x8*)(dst + (size_t)i * 8) = v;
}

// ---------- RoPE tables ----------
__global__ void rope_tab_k(float* __restrict__ cosT, float* __restrict__ sinT) {
    int i = blockIdx.x * blockDim.x + threadIdx.x;   // 8192 total
    int l = i >> 5, fi = i & 31;
    float inv = powf(10000.f, -2.f * (float)fi / 64.f);
    float ang = (float)l * inv;
    cosT[i] = cosf(ang);
    sinT[i] = sinf(ang);
}

// ---------- 128x128 GEMM, BK=32, dbuf, 4 blocks/CU ----------
// 256-thread blocks (4 waves 2Mx2N), wave tile 64x64, acc[4][4] (~120 regs incl
// AGPR on unified file — fits the 128-reg budget at 4 waves/SIMD). LDS 2 x 16 KiB
// = 32 KiB -> 4 blocks/CU. Each SIMD hosts 4 waves from 4 INDEPENDENT barrier
// domains: per-tile VMC(0)+BAR drain of one block is filled by the other three
// (m114 TLP). Round-11 lesson: never squeeze the reg budget below arch+acc
// (~120) — launch_bounds(512,6) spilled acc to scratch (851 us).
// Depth-1 prefetch, one VMC(0)+BAR per K-tile (collective-guard protocol,
// rounds 4/5). Depth>=2 rejected (round 10: L2 thrash, +70MB refetch).
// Swizzle f(row)=(row>>1)&3: conflict-free (0 conflicts, rounds 6-10).

__device__ __forceinline__ void stage128x32(const ushort_t* __restrict__ src,
                                            ushort_t* chunk, int tid, int kk) {
#pragma unroll
    for (int j = 0; j < 2; ++j) {
        int row = (tid >> 2) + j * 64;        // 128 rows x 4 slots, 256 threads
        int gslot = (tid & 3) ^ ((row >> 1) & 3);
        gload16(src + (size_t)row * 1024 + kk + gslot * 8,
                chunk + (size_t)tid * 8 + (size_t)j * 2048);
    }
}

__device__ __forceinline__ s16x8 rd32(const ushort_t* chunk, int wrow, int f, int lane) {
    int row = wrow * 64 + f * 16 + (lane & 15);
    int slot = (lane >> 4) ^ ((row >> 1) & 3);
    return *(const s16x8*)&chunk[row * 32 + (slot << 3)];
}

// MODE 0: fused QKV (N=3072 -> q/k/v bf16 + bias + rope on q,k), ntn=24
// MODE 1: out-proj (N=1024 -> fp32 + bias), ntn=8
template <int MODE>
__global__ __launch_bounds__(256, 4) void gemm128(const ushort_t* __restrict__ A,
                                                  const ushort_t* __restrict__ Wt,
                                                  const float* __restrict__ bz0,
                                                  const float* __restrict__ bz1,
                                                  const float* __restrict__ bz2,
                                                  ushort_t* __restrict__ o0,
                                                  ushort_t* __restrict__ o1,
                                                  ushort_t* __restrict__ o2,
                                                  float* __restrict__ of,
                                                  const float* __restrict__ cosT,
                                                  const float* __restrict__ sinT,
                                                  int ntn) {
    __shared__ ushort_t lds[2][8192];   // per buf: A [0..4096), B [4096..8192)

    const int nwg = 128 * ntn;
    const int orig = blockIdx.x;
    const int wg = (orig % 8) * (nwg / 8) + orig / 8;   // bijective XCD swizzle (nwg%8==0)
    const int tn = wg % ntn, tm = wg / ntn;             // tn fastest: A-panel L2 reuse

    const int tid = threadIdx.x, lane = tid & 63, wid = tid >> 6;
    const int wm = wid >> 1, wn = wid & 1;

    f32x4 acc[4][4];
#pragma unroll
    for (int i = 0; i < 4; ++i)
#pragma unroll
        for (int j = 0; j < 4; ++j) acc[i][j] = (f32x4){0.f, 0.f, 0.f, 0.f};

    const ushort_t* Abase = A + (size_t)(tm * 128) * 1024;
    const ushort_t* Bbase = Wt + (size_t)(tn * 128) * 1024;

    // ---- prologue: stage tile 0 into buf 0; collective guard ----
    stage128x32(Abase, &lds[0][0], tid, 0);
    stage128x32(Bbase, &lds[0][4096], tid, 0);
    VMC(0);
    BAR();

    // ---- main loop: 32 K-tiles, one barrier each, depth-1 prefetch ----
#pragma unroll 1
    for (int u = 0; u < 32; ++u) {
        const int cur = u & 1;
        const ushort_t* cA = &lds[cur][0];
        const ushort_t* cB = &lds[cur][4096];
        ushort_t* nA = &lds[cur ^ 1][0];
        ushort_t* nB = &lds[cur ^ 1][4096];
        const int kt = (u + 1 < 32 ? u + 1 : 31) * 32;   // clamp: tail writes unread buf
        s16x8 b_[4], a_[2], a2_[2];

#pragma unroll
        for (int n = 0; n < 4; ++n) b_[n] = rd32(cB, wn, n, lane);
        a_[0] = rd32(cA, wm, 0, lane); a_[1] = rd32(cA, wm, 1, lane);
        stage128x32(Abase, nA, tid, kt);
        LGK0();
        __builtin_amdgcn_s_setprio(1);
#pragma unroll
        for (int m = 0; m < 2; ++m)
#pragma unroll
            for (int n = 0; n < 4; ++n)
                acc[m][n] = __builtin_amdgcn_mfma_f32_16x16x32_bf16(a_[m], b_[n], acc[m][n], 0, 0, 0);
        __builtin_amdgcn_s_setprio(0);

        a2_[0] = rd32(cA, wm, 2, lane); a2_[1] = rd32(cA, wm, 3, lane);
        stage128x32(Bbase, nB, tid, kt);
        LGK0();
        __builtin_amdgcn_s_setprio(1);
#pragma unroll
        for (int m = 0; m < 2; ++m)
#pragma unroll
            for (int n = 0; n < 4; ++n)
                acc[m + 2][n] = __builtin_amdgcn_mfma_f32_16x16x32_bf16(a2_[m], b_[n], acc[m + 2][n], 0, 0, 0);
        __builtin_amdgcn_s_setprio(0);

        VMC(0);    // tile u+1 fully landed (per-wave) ...
        BAR();     // ... made collective; also closes WAR window for next stage
    }

    // ---- epilogue ----
    const int rb0 = tm * 128 + wm * 64 + ((lane >> 4) << 2);
    if (MODE == 0) {
        const int zz = tn >> 3;                                  // uniform per block
        const float* bias = (zz == 0) ? bz0 : (zz == 1) ? bz1 : bz2;
        ushort_t* outp = (zz == 0) ? o0 : (zz == 1) ? o1 : o2;
        const bool rope = (zz < 2);
        const int cb = (tn & 7) * 128 + wn * 64;
#pragma unroll
        for (int m = 0; m < 4; ++m) {
#pragma unroll
            for (int n = 0; n < 4; ++n) {
                int col = cb + n * 16 + (lane & 15);
                float bv_ = bias[col];
                int rb = rb0 + m * 16;
#pragma unroll
                for (int r = 0; r < 4; ++r) {
                    float v = acc[m][n][r] + bv_;
                    float res;
                    if (rope) {
                        int l = (rb + r) & 255;
                        int fi = (col & 63) >> 1;
                        float c = cosT[l * 32 + fi], s = sinT[l * 32 + fi];
                        float partner = __shfl_xor(v, 1);
                        res = (col & 1) ? (v * c + partner * s) : (v * c - partner * s);
                    } else {
                        res = v;
                    }
                    outp[(size_t)(rb + r) * 1024 + col] = f2bf(res);
                }
            }
        }
    } else {
        const int cfull = tn * 128 + wn * 64;
#pragma unroll
        for (int m = 0; m < 4; ++m) {
#pragma unroll
            for (int n = 0; n < 4; ++n) {
                int col = cfull + n * 16 + (lane & 15);
                float bv_ = bz0[col];
                int rb = rb0 + m * 16;
#pragma unroll
                for (int r = 0; r < 4; ++r)
                    of[(size_t)(rb + r) * 1024 + col] = acc[m][n][r] + bv_;
            }
        }
    }
}

// ---------- fused causal attention per (b,h) (unchanged from round 8) ----------
__global__ __launch_bounds__(512, 4) void attn_kernel(const ushort_t* __restrict__ qb,
                                                      const ushort_t* __restrict__ kb,
                                                      const ushort_t* __restrict__ vb,
                                                      ushort_t* __restrict__ ab) {
    __shared__ ushort_t Ks[256 * 72];      // 36864 B
    __shared__ ushort_t Vt[64 * 264];      // 33792 B
    __shared__ ushort_t Ps[8][16 * 40];    // 10240 B
    const int bh = blockIdx.x, b = bh >> 4, h = bh & 15;
    const int tid = threadIdx.x, lane = tid & 63, wid = tid >> 6;
    const size_t base = (size_t)b * 256 * 1024 + (size_t)h * 64;

#pragma unroll
    for (int it = 0; it < 4; ++it) {
        int c = tid + it * 512;
        int row = c >> 3, seg = c & 7;
        *(s16x8*)&Ks[row * 72 + seg * 8] =
            *(const s16x8*)&kb[base + (size_t)row * 1024 + seg * 8];
    }
#pragma unroll
    for (int it = 0; it < 4; ++it) {
        int c = tid + it * 512;
        int k = c >> 3, seg = c & 7;
        s16x8 v8 = *(const s16x8*)&vb[base + (size_t)k * 1024 + seg * 8];
#pragma unroll
        for (int j = 0; j < 8; ++j)
            Vt[(seg * 8 + j) * 264 + k] = (ushort_t)v8[j];
    }
    __syncthreads();   // only barrier in the kernel

#pragma unroll
    for (int ch = 0; ch < 2; ++ch) {
        const int q0 = wid * 32 + ch * 16;
        const int ntop = q0 >> 4;
        s16x8 aq0 = *(const s16x8*)&qb[base + (size_t)(q0 + (lane & 15)) * 1024 + ((lane >> 4) << 3)];
        s16x8 aq1 = *(const s16x8*)&qb[base + (size_t)(q0 + (lane & 15)) * 1024 + 32 + ((lane >> 4) << 3)];

        f32x4 sacc[16];
#pragma unroll
        for (int n = 0; n < 16; ++n) sacc[n] = (f32x4){0.f, 0.f, 0.f, 0.f};
#pragma unroll
        for (int n = 0; n < 16; ++n) {
            if (n <= ntop) {
                const int kr = (n * 16 + (lane & 15)) * 72 + ((lane >> 4) << 3);
                s16x8 b0 = *(const s16x8*)&Ks[kr];
                s16x8 b1 = *(const s16x8*)&Ks[kr + 32];
                sacc[n] = __builtin_amdgcn_mfma_f32_16x16x32_bf16(aq0, b0, sacc[n], 0, 0, 0);
                sacc[n] = __builtin_amdgcn_mfma_f32_16x16x32_bf16(aq1, b1, sacc[n], 0, 0, 0);
            }
        }

        float rinv[4];
#pragma unroll
        for (int r = 0; r < 4; ++r) {
            const int row = q0 + ((lane >> 4) << 2) + r;
            float m = -1e30f;
#pragma unroll
            for (int n = 0; n < 16; ++n) {
                int col = n * 16 + (lane & 15);
                float v = (col <= row) ? sacc[n][r] * 0.125f : -1e30f;
                sacc[n][r] = v;
                m = fmaxf(m, v);
            }
            m = fmaxf(m, __shfl_xor(m, 1));
            m = fmaxf(m, __shfl_xor(m, 2));
            m = fmaxf(m, __shfl_xor(m, 4));
            m = fmaxf(m, __shfl_xor(m, 8));
            float sum = 0.f;
#pragma unroll
            for (int n = 0; n < 16; ++n) {
                float p = __expf(sacc[n][r] - m);
                sacc[n][r] = p;
                sum += p;
            }
            sum += __shfl_xor(sum, 1);
            sum += __shfl_xor(sum, 2);
            sum += __shfl_xor(sum, 4);
            sum += __shfl_xor(sum, 8);
            rinv[r] = 1.f / sum;
        }

        f32x4 oa[4];
#pragma unroll
        for (int dt = 0; dt < 4; ++dt) oa[dt] = (f32x4){0.f, 0.f, 0.f, 0.f};
        const int kstop = q0 >> 5;
#pragma unroll
        for (int ks = 0; ks < 8; ++ks) {
            if (ks <= kstop) {
#pragma unroll
                for (int nl = 0; nl < 2; ++nl) {
                    const int n = 2 * ks + nl;
#pragma unroll
                    for (int r = 0; r < 4; ++r)
                        Ps[wid][(((lane >> 4) << 2) + r) * 40 + nl * 16 + (lane & 15)] =
                            f2bf(sacc[n][r]);
                }
                s16x8 pf = *(const s16x8*)&Ps[wid][(lane & 15) * 40 + ((lane >> 4) << 3)];
#pragma unroll
                for (int dt = 0; dt < 4; ++dt) {
                    s16x8 vf = *(const s16x8*)&Vt[(dt * 16 + (lane & 15)) * 264 + ks * 32 + ((lane >> 4) << 3)];
                    oa[dt] = __builtin_amdgcn_mfma_f32_16x16x32_bf16(pf, vf, oa[dt], 0, 0, 0);
                }
            }
        }
#pragma unroll
        for (int dt = 0; dt < 4; ++dt) {
#pragma unroll
            for (int r = 0; r < 4; ++r) {
                int row = q0 + ((lane >> 4) << 2) + r;
                int col = h * 64 + dt * 16 + (lane & 15);
                ab[(size_t)(b * 256 + row) * 1024 + col] = f2bf(oa[dt][r] * rinv[r]);
            }
        }
    }
}

// ---------- launch ----------
extern "C" void kernel_launch(void* const* d_in, const int* in_sizes, int n_in,
                              void* d_out, int out_size, void* d_ws, size_t ws_size,
                              hipStream_t stream) {
    (void)in_sizes; (void)n_in; (void)out_size;
    const float* x  = (const float*)d_in[0];
    const float* Wq = (const float*)d_in[1];
    const float* bq = (const float*)d_in[2];
    const float* Wk = (const float*)d_in[3];
    const float* bk = (const float*)d_in[4];
    const float* Wv = (const float*)d_in[5];
    const float* bv = (const float*)d_in[6];
    const float* Wo = (const float*)d_in[7];
    const float* bo = (const float*)d_in[8];
    float* out = (float*)d_out;

    const size_t M = 16384, E = 1024;
    char* ws = (char*)d_ws;
    ushort_t* xb   = (ushort_t*)ws;          // M*E (aliased as attn out later)
    ushort_t* wqkv = xb + M * E;             // 4*E*E, concat [Wq;Wk;Wv;Wo]
    ushort_t* wob  = wqkv + 3 * E * E;
    ushort_t* qb   = wob + E * E;
    ushort_t* kb   = qb + M * E;
    ushort_t* vb   = kb + M * E;
    float* cosT    = (float*)(vb + M * E);
    float* sinT    = cosT + 256 * 32;
    ushort_t* ab   = xb;

    size_t need = (4 * M * E + 4 * E * E) * sizeof(ushort_t) + 2 * 256 * 32 * sizeof(float);
    if (ws_size < need) return;

    cvt_bf16<<<8192, 256, 0, stream>>>(x, xb, (int)(M * E / 8));
    cvt_w4<<<dim3(512, 4), 256, 0, stream>>>(Wq, Wk, Wv, Wo, wqkv);
    rope_tab_k<<<32, 256, 0, stream>>>(cosT, sinT);

    gemm128<0><<<3072, 256, 0, stream>>>(xb, wqkv, bq, bk, bv, qb, kb, vb, nullptr,
                                         cosT, sinT, 24);
    attn_kernel<<<1024, 512, 0, stream>>>(qb, kb, vb, ab);
    gemm128<1><<<1024, 256, 0, stream>>>(ab, wob, bo, nullptr, nullptr,
                                         nullptr, nullptr, nullptr, out, nullptr, nullptr, 8);
}

// Round 13
// 239.177 us; speedup vs baseline: 4.4001x; 1.1078x over previous
//
#include <hip/hip_runtime.h>
#include <hip/hip_bf16.h>

typedef __attribute__((ext_vector_type(4))) float f32x4;
typedef __attribute__((ext_vector_type(8))) short s16x8;
typedef unsigned short ushort_t;

// ---------- helpers ----------
__device__ __forceinline__ ushort_t f2bf(float f) {
    union { float f; unsigned u; } v; v.f = f;
    unsigned r = v.u + 0x7fffu + ((v.u >> 16) & 1u);   // RNE
    return (ushort_t)(r >> 16);
}

__device__ __forceinline__ void gload16(const ushort_t* g, ushort_t* l) {
    __builtin_amdgcn_global_load_lds(
        (const __attribute__((address_space(1))) unsigned int*)g,
        (__attribute__((address_space(3))) unsigned int*)l,
        16, 0, 0);
}

#define BAR()  asm volatile("s_barrier" ::: "memory")
#define LGK0() do { asm volatile("s_waitcnt lgkmcnt(0)" ::: "memory"); __builtin_amdgcn_sched_barrier(0); } while (0)
#define VMC(n) asm volatile("s_waitcnt vmcnt(" #n ")" ::: "memory")

// ---------- fp32 -> bf16 conversion (8 elems/thread) ----------
__global__ void cvt_bf16(const float* __restrict__ in, ushort_t* __restrict__ out, int n8) {
    int i = blockIdx.x * blockDim.x + threadIdx.x;
    if (i >= n8) return;
    const float4* p = (const float4*)in;
    float4 a = p[2 * i], b = p[2 * i + 1];
    s16x8 v;
    v[0] = (short)f2bf(a.x); v[1] = (short)f2bf(a.y);
    v[2] = (short)f2bf(a.z); v[3] = (short)f2bf(a.w);
    v[4] = (short)f2bf(b.x); v[5] = (short)f2bf(b.y);
    v[6] = (short)f2bf(b.z); v[7] = (short)f2bf(b.w);
    *(s16x8*)(out + (size_t)i * 8) = v;
}

// 4 weight matrices (E*E each) -> contiguous bf16 [Wq;Wk;Wv;Wo]
__global__ void cvt_w4(const float* __restrict__ w0, const float* __restrict__ w1,
                       const float* __restrict__ w2, const float* __restrict__ w3,
                       ushort_t* __restrict__ out) {
    const float* src = (blockIdx.y == 0) ? w0 : (blockIdx.y == 1) ? w1
                     : (blockIdx.y == 2) ? w2 : w3;
    ushort_t* dst = out + (size_t)blockIdx.y * 1024 * 1024;
    int i = blockIdx.x * blockDim.x + threadIdx.x;   // 131072 per matrix
    const float4* p = (const float4*)src;
    float4 a = p[2 * i], b = p[2 * i + 1];
    s16x8 v;
    v[0] = (short)f2bf(a.x); v[1] = (short)f2bf(a.y);
    v[2] = (short)f2bf(a.z); v[3] = (short)f2bf(a.w);
    v[4] = (short)f2bf(b.x); v[5] = (short)f2bf(b.y);
    v[6] = (short)f2bf(b.z); v[7] = (short)f2bf(b.w);
    *(s16x8*)(dst + (size_t)i * 8) = v;
}

// ---------- RoPE tables ----------
__global__ void rope_tab_k(float* __restrict__ cosT, float* __restrict__ sinT) {
    int i = blockIdx.x * blockDim.x + threadIdx.x;   // 8192 total
    int l = i >> 5, fi = i & 31;
    float inv = powf(10000.f, -2.f * (float)fi / 64.f);
    float ang = (float)l * inv;
    cosT[i] = cosf(ang);
    sinT[i] = sinf(ang);
}

// ---------- 128x256 GEMM, BK=32, dbuf, 2 blocks/CU (round-9 optimum) ----------
// 8 waves (2Mx4N), wave tile 64x64, acc[4][4] (~120 regs incl AGPR on unified
// file); LDS 2 x 24 KiB = 48 KiB -> 2 blocks/CU at the legal 128-reg budget
// (launch_bounds(512,4)). Depth-1 prefetch, ONE VMC(0)+BAR per K-tile
// (collective guard: counted/zero vmcnt must precede a barrier to be cross-wave
// valid — round-4 NaN lesson). Co-resident block fills the drain stall (m114).
// Ledger: depth-2 (r10: L2 thrash, +70MB refetch, −4%), launch_bounds(512,6)
// (r11: acc spill to scratch, 5.9x), 128x128 4-block (r12: same waves/CU,
// +1.5x traffic, −18%), 8-phase/1-barrier/256^2 (r2-7: 26-27% plateau).
// Swizzle f(row)=(row>>1)&3: conflict-free (0 conflicts, rounds 6-12).

__device__ __forceinline__ void stageA32(const ushort_t* __restrict__ src,
                                         ushort_t* chunk, int tid, int kk) {
    int row = tid >> 2;                       // 128 rows x 4 slots
    int gslot = (tid & 3) ^ ((row >> 1) & 3);
    gload16(src + (size_t)row * 1024 + kk + gslot * 8, chunk + (size_t)tid * 8);
}
__device__ __forceinline__ void stageB32(const ushort_t* __restrict__ src,
                                         ushort_t* chunk, int tid, int kk) {
#pragma unroll
    for (int j = 0; j < 2; ++j) {
        int row = (tid >> 2) + j * 128;       // 256 rows x 4 slots
        int gslot = (tid & 3) ^ ((row >> 1) & 3);
        gload16(src + (size_t)row * 1024 + kk + gslot * 8,
                chunk + (size_t)tid * 8 + (size_t)j * 4096);
    }
}

__device__ __forceinline__ s16x8 rdA32(const ushort_t* chunk, int wm, int m, int lane) {
    int row = wm * 64 + m * 16 + (lane & 15);
    int slot = (lane >> 4) ^ ((row >> 1) & 3);
    return *(const s16x8*)&chunk[row * 32 + (slot << 3)];
}
__device__ __forceinline__ s16x8 rdB32(const ushort_t* chunk, int wn, int n, int lane) {
    int row = wn * 64 + n * 16 + (lane & 15);
    int slot = (lane >> 4) ^ ((row >> 1) & 3);
    return *(const s16x8*)&chunk[row * 32 + (slot << 3)];
}

// MODE 0: fused QKV (N=3072 -> q/k/v bf16 + bias + rope on q,k), ntn=12
// MODE 1: out-proj (N=1024 -> fp32 + bias), ntn=4
template <int MODE>
__global__ __launch_bounds__(512, 4) void gemm128(const ushort_t* __restrict__ A,
                                                  const ushort_t* __restrict__ Wt,
                                                  const float* __restrict__ bz0,
                                                  const float* __restrict__ bz1,
                                                  const float* __restrict__ bz2,
                                                  ushort_t* __restrict__ o0,
                                                  ushort_t* __restrict__ o1,
                                                  ushort_t* __restrict__ o2,
                                                  float* __restrict__ of,
                                                  const float* __restrict__ cosT,
                                                  const float* __restrict__ sinT,
                                                  int ntn) {
    __shared__ ushort_t lds[2][12288];   // per buf: A [0..4096), B [4096..12288)

    const int nwg = 128 * ntn;
    const int orig = blockIdx.x;
    const int wg = (orig % 8) * (nwg / 8) + orig / 8;   // bijective XCD swizzle (nwg%8==0)
    const int tn = wg % ntn, tm = wg / ntn;             // tn fastest: A-panel L2 reuse

    const int tid = threadIdx.x, lane = tid & 63, wid = tid >> 6;
    const int wm = wid >> 2, wn = wid & 3;

    f32x4 acc[4][4];
#pragma unroll
    for (int i = 0; i < 4; ++i)
#pragma unroll
        for (int j = 0; j < 4; ++j) acc[i][j] = (f32x4){0.f, 0.f, 0.f, 0.f};

    const ushort_t* Abase = A + (size_t)(tm * 128) * 1024;
    const ushort_t* Bbase = Wt + (size_t)(tn * 256) * 1024;

    // ---- prologue: stage tile 0 into buf 0; collective guard ----
    stageA32(Abase, &lds[0][0], tid, 0);
    stageB32(Bbase, &lds[0][4096], tid, 0);
    VMC(0);
    BAR();

    // ---- main loop: 32 K-tiles, one barrier each, depth-1 prefetch ----
#pragma unroll 1
    for (int u = 0; u < 32; ++u) {
        const int cur = u & 1;
        const ushort_t* cA = &lds[cur][0];
        const ushort_t* cB = &lds[cur][4096];
        ushort_t* nA = &lds[cur ^ 1][0];
        ushort_t* nB = &lds[cur ^ 1][4096];
        const int kt = (u + 1 < 32 ? u + 1 : 31) * 32;   // clamp: tail writes unread buf
        s16x8 b_[4], a_[2], a2_[2];

#pragma unroll
        for (int n = 0; n < 4; ++n) b_[n] = rdB32(cB, wn, n, lane);
        a_[0] = rdA32(cA, wm, 0, lane); a_[1] = rdA32(cA, wm, 1, lane);
        stageA32(Abase, nA, tid, kt);
        LGK0();
        __builtin_amdgcn_s_setprio(1);
#pragma unroll
        for (int m = 0; m < 2; ++m)
#pragma unroll
            for (int n = 0; n < 4; ++n)
                acc[m][n] = __builtin_amdgcn_mfma_f32_16x16x32_bf16(a_[m], b_[n], acc[m][n], 0, 0, 0);
        __builtin_amdgcn_s_setprio(0);

        a2_[0] = rdA32(cA, wm, 2, lane); a2_[1] = rdA32(cA, wm, 3, lane);
        stageB32(Bbase, nB, tid, kt);
        LGK0();
        __builtin_amdgcn_s_setprio(1);
#pragma unroll
        for (int m = 0; m < 2; ++m)
#pragma unroll
            for (int n = 0; n < 4; ++n)
                acc[m + 2][n] = __builtin_amdgcn_mfma_f32_16x16x32_bf16(a2_[m], b_[n], acc[m + 2][n], 0, 0, 0);
        __builtin_amdgcn_s_setprio(0);

        VMC(0);    // tile u+1 fully landed (per-wave) ...
        BAR();     // ... made collective; also closes WAR window for next stage
    }

    // ---- epilogue ----
    const int rb0 = tm * 128 + wm * 64 + ((lane >> 4) << 2);
    if (MODE == 0) {
        const int zz = tn >> 2;                                  // uniform per block
        const float* bias = (zz == 0) ? bz0 : (zz == 1) ? bz1 : bz2;
        ushort_t* outp = (zz == 0) ? o0 : (zz == 1) ? o1 : o2;
        const bool rope = (zz < 2);
        const int cb = (tn & 3) * 256 + wn * 64;
#pragma unroll
        for (int m = 0; m < 4; ++m) {
#pragma unroll
            for (int n = 0; n < 4; ++n) {
                int col = cb + n * 16 + (lane & 15);
                float bv_ = bias[col];
                int rb = rb0 + m * 16;
#pragma unroll
                for (int r = 0; r < 4; ++r) {
                    float v = acc[m][n][r] + bv_;
                    float res;
                    if (rope) {
                        int l = (rb + r) & 255;
                        int fi = (col & 63) >> 1;
                        float c = cosT[l * 32 + fi], s = sinT[l * 32 + fi];
                        float partner = __shfl_xor(v, 1);
                        res = (col & 1) ? (v * c + partner * s) : (v * c - partner * s);
                    } else {
                        res = v;
                    }
                    outp[(size_t)(rb + r) * 1024 + col] = f2bf(res);
                }
            }
        }
    } else {
        const int cfull = tn * 256 + wn * 64;
#pragma unroll
        for (int m = 0; m < 4; ++m) {
#pragma unroll
            for (int n = 0; n < 4; ++n) {
                int col = cfull + n * 16 + (lane & 15);
                float bv_ = bz0[col];
                int rb = rb0 + m * 16;
#pragma unroll
                for (int r = 0; r < 4; ++r)
                    of[(size_t)(rb + r) * 1024 + col] = acc[m][n][r] + bv_;
            }
        }
    }
}

// ---------- fused causal attention per (b,h) (round-8 structure) ----------
__global__ __launch_bounds__(512, 4) void attn_kernel(const ushort_t* __restrict__ qb,
                                                      const ushort_t* __restrict__ kb,
                                                      const ushort_t* __restrict__ vb,
                                                      ushort_t* __restrict__ ab) {
    __shared__ ushort_t Ks[256 * 72];      // 36864 B
    __shared__ ushort_t Vt[64 * 264];      // 33792 B
    __shared__ ushort_t Ps[8][16 * 40];    // 10240 B
    const int bh = blockIdx.x, b = bh >> 4, h = bh & 15;
    const int tid = threadIdx.x, lane = tid & 63, wid = tid >> 6;
    const size_t base = (size_t)b * 256 * 1024 + (size_t)h * 64;

#pragma unroll
    for (int it = 0; it < 4; ++it) {
        int c = tid + it * 512;
        int row = c >> 3, seg = c & 7;
        *(s16x8*)&Ks[row * 72 + seg * 8] =
            *(const s16x8*)&kb[base + (size_t)row * 1024 + seg * 8];
    }
#pragma unroll
    for (int it = 0; it < 4; ++it) {
        int c = tid + it * 512;
        int k = c >> 3, seg = c & 7;
        s16x8 v8 = *(const s16x8*)&vb[base + (size_t)k * 1024 + seg * 8];
#pragma unroll
        for (int j = 0; j < 8; ++j)
            Vt[(seg * 8 + j) * 264 + k] = (ushort_t)v8[j];
    }
    __syncthreads();   // only barrier in the kernel

#pragma unroll
    for (int ch = 0; ch < 2; ++ch) {
        const int q0 = wid * 32 + ch * 16;
        const int ntop = q0 >> 4;
        s16x8 aq0 = *(const s16x8*)&qb[base + (size_t)(q0 + (lane & 15)) * 1024 + ((lane >> 4) << 3)];
        s16x8 aq1 = *(const s16x8*)&qb[base + (size_t)(q0 + (lane & 15)) * 1024 + 32 + ((lane >> 4) << 3)];

        f32x4 sacc[16];
#pragma unroll
        for (int n = 0; n < 16; ++n) sacc[n] = (f32x4){0.f, 0.f, 0.f, 0.f};
#pragma unroll
        for (int n = 0; n < 16; ++n) {
            if (n <= ntop) {
                const int kr = (n * 16 + (lane & 15)) * 72 + ((lane >> 4) << 3);
                s16x8 b0 = *(const s16x8*)&Ks[kr];
                s16x8 b1 = *(const s16x8*)&Ks[kr + 32];
                sacc[n] = __builtin_amdgcn_mfma_f32_16x16x32_bf16(aq0, b0, sacc[n], 0, 0, 0);
                sacc[n] = __builtin_amdgcn_mfma_f32_16x16x32_bf16(aq1, b1, sacc[n], 0, 0, 0);
            }
        }

        float rinv[4];
#pragma unroll
        for (int r = 0; r < 4; ++r) {
            const int row = q0 + ((lane >> 4) << 2) + r;
            float m = -1e30f;
#pragma unroll
            for (int n = 0; n < 16; ++n) {
                int col = n * 16 + (lane & 15);
                float v = (col <= row) ? sacc[n][r] * 0.125f : -1e30f;
                sacc[n][r] = v;
                m = fmaxf(m, v);
            }
            m = fmaxf(m, __shfl_xor(m, 1));
            m = fmaxf(m, __shfl_xor(m, 2));
            m = fmaxf(m, __shfl_xor(m, 4));
            m = fmaxf(m, __shfl_xor(m, 8));
            float sum = 0.f;
#pragma unroll
            for (int n = 0; n < 16; ++n) {
                float p = __expf(sacc[n][r] - m);
                sacc[n][r] = p;
                sum += p;
            }
            sum += __shfl_xor(sum, 1);
            sum += __shfl_xor(sum, 2);
            sum += __shfl_xor(sum, 4);
            sum += __shfl_xor(sum, 8);
            rinv[r] = 1.f / sum;
        }

        f32x4 oa[4];
#pragma unroll
        for (int dt = 0; dt < 4; ++dt) oa[dt] = (f32x4){0.f, 0.f, 0.f, 0.f};
        const int kstop = q0 >> 5;
#pragma unroll
        for (int ks = 0; ks < 8; ++ks) {
            if (ks <= kstop) {
#pragma unroll
                for (int nl = 0; nl < 2; ++nl) {
                    const int n = 2 * ks + nl;
#pragma unroll
                    for (int r = 0; r < 4; ++r)
                        Ps[wid][(((lane >> 4) << 2) + r) * 40 + nl * 16 + (lane & 15)] =
                            f2bf(sacc[n][r]);
                }
                s16x8 pf = *(const s16x8*)&Ps[wid][(lane & 15) * 40 + ((lane >> 4) << 3)];
#pragma unroll
                for (int dt = 0; dt < 4; ++dt) {
                    s16x8 vf = *(const s16x8*)&Vt[(dt * 16 + (lane & 15)) * 264 + ks * 32 + ((lane >> 4) << 3)];
                    oa[dt] = __builtin_amdgcn_mfma_f32_16x16x32_bf16(pf, vf, oa[dt], 0, 0, 0);
                }
            }
        }
#pragma unroll
        for (int dt = 0; dt < 4; ++dt) {
#pragma unroll
            for (int r = 0; r < 4; ++r) {
                int row = q0 + ((lane >> 4) << 2) + r;
                int col = h * 64 + dt * 16 + (lane & 15);
                ab[(size_t)(b * 256 + row) * 1024 + col] = f2bf(oa[dt][r] * rinv[r]);
            }
        }
    }
}

// ---------- launch ----------
extern "C" void kernel_launch(void* const* d_in, const int* in_sizes, int n_in,
                              void* d_out, int out_size, void* d_ws, size_t ws_size,
                              hipStream_t stream) {
    (void)in_sizes; (void)n_in; (void)out_size;
    const float* x  = (const float*)d_in[0];
    const float* Wq = (const float*)d_in[1];
    const float* bq = (const float*)d_in[2];
    const float* Wk = (const float*)d_in[3];
    const float* bk = (const float*)d_in[4];
    const float* Wv = (const float*)d_in[5];
    const float* bv = (const float*)d_in[6];
    const float* Wo = (const float*)d_in[7];
    const float* bo = (const float*)d_in[8];
    float* out = (float*)d_out;

    const size_t M = 16384, E = 1024;
    char* ws = (char*)d_ws;
    ushort_t* xb   = (ushort_t*)ws;          // M*E (aliased as attn out later)
    ushort_t* wqkv = xb + M * E;             // 4*E*E, concat [Wq;Wk;Wv;Wo]
    ushort_t* wob  = wqkv + 3 * E * E;
    ushort_t* qb   = wob + E * E;
    ushort_t* kb   = qb + M * E;
    ushort_t* vb   = kb + M * E;
    float* cosT    = (float*)(vb + M * E);
    float* sinT    = cosT + 256 * 32;
    ushort_t* ab   = xb;

    size_t need = (4 * M * E + 4 * E * E) * sizeof(ushort_t) + 2 * 256 * 32 * sizeof(float);
    if (ws_size < need) return;

    cvt_bf16<<<8192, 256, 0, stream>>>(x, xb, (int)(M * E / 8));
    cvt_w4<<<dim3(512, 4), 256, 0, stream>>>(Wq, Wk, Wv, Wo, wqkv);
    rope_tab_k<<<32, 256, 0, stream>>>(cosT, sinT);

    gemm128<0><<<1536, 512, 0, stream>>>(xb, wqkv, bq, bk, bv, qb, kb, vb, nullptr,
                                         cosT, sinT, 12);
    attn_kernel<<<1024, 512, 0, stream>>>(qb, kb, vb, ab);
    gemm128<1><<<512, 512, 0, stream>>>(ab, wob, bo, nullptr, nullptr,
                                        nullptr, nullptr, nullptr, out, nullptr, nullptr, 4);
}